// Round 8
// baseline (314.891 us; speedup 1.0000x reference)
//
#include <hip/hip_runtime.h>

#define N_NODES 50000
#define N_EDGES 800000
#define N_GRAPHS 256
#define NCB 196        // coarse buckets = ceil(50000/256), dst>>8
#define CHUNK 3125     // edges per block in coarse passes (256 blocks)
#define GH_LEN (NCB * 256)   // 50176

// ---------------------------------------------------------------------------
// Dense GEMMs, v2: LDS only for A (17KB, [k][m] stride 68); B fragments read
// directly from global (4 unique 16B/wave, L2-resident weights) — removes the
// Bs ds_read_b128 that made v1 LDS-BW-bound (4 SIMDs share one LDS pipe).
// Micro-tile 4m x 8n -> 32 FMA per 1 LDS b128.
// ---------------------------------------------------------------------------

// Layer 2: X=relu(h1) (N x 128), W1/W2 (128 x 64). HW1 = XW1 ; AGG = XW2 + b.
__global__ __launch_bounds__(256)
void dense2_kernel(const float* __restrict__ X, const float* __restrict__ W1,
                   const float* __restrict__ W2, const float* __restrict__ Bias,
                   float* __restrict__ HW1, float* __restrict__ AGG)
{
    __shared__ float As[64 * 68];
    const int tid = threadIdx.x;
    const int tm = tid & 15;
    const int tn = tid >> 4;
    const int m0 = blockIdx.x * 64;

    float acc0[4][4], acc1[4][4];
    #pragma unroll
    for (int i = 0; i < 4; ++i)
        #pragma unroll
        for (int j = 0; j < 4; ++j) { acc0[i][j] = 0.f; acc1[i][j] = 0.f; }

    for (int kk = 0; kk < 128; kk += 64) {
        __syncthreads();
        for (int i = tid; i < 64 * 64; i += 256) {
            int n = i >> 6, k = i & 63;
            int gn = m0 + n;
            float v = (gn < N_NODES) ? fmaxf(X[(size_t)gn * 128 + kk + k], 0.f) : 0.f;
            As[k * 68 + n] = v;
        }
        __syncthreads();
        #pragma unroll 4
        for (int k = 0; k < 64; ++k) {
            const float4 a  = *(const float4*)(As + k * 68 + 4 * tm);
            const float4 b0 = *(const float4*)(W1 + (kk + k) * 64 + 4 * tn);
            const float4 b1 = *(const float4*)(W2 + (kk + k) * 64 + 4 * tn);
            float av[4] = {a.x, a.y, a.z, a.w};
            float b0v[4] = {b0.x, b0.y, b0.z, b0.w};
            float b1v[4] = {b1.x, b1.y, b1.z, b1.w};
            #pragma unroll
            for (int i = 0; i < 4; ++i)
                #pragma unroll
                for (int j = 0; j < 4; ++j) {
                    acc0[i][j] = fmaf(av[i], b0v[j], acc0[i][j]);
                    acc1[i][j] = fmaf(av[i], b1v[j], acc1[i][j]);
                }
        }
    }

    const int c = 4 * tn;
    const float4 bias = *(const float4*)(Bias + c);
    #pragma unroll
    for (int i = 0; i < 4; ++i) {
        int gm = m0 + 4 * tm + i;
        if (gm >= N_NODES) continue;
        *(float4*)(HW1 + (size_t)gm * 64 + c) =
            make_float4(acc0[i][0], acc0[i][1], acc0[i][2], acc0[i][3]);
        *(float4*)(AGG + (size_t)gm * 64 + c) =
            make_float4(acc1[i][0] + bias.x, acc1[i][1] + bias.y,
                        acc1[i][2] + bias.z, acc1[i][3] + bias.w);
    }
}

// Layer 1: CI (N x 64) @ wpack (64 x 128) + b -> H1 (N x 128). Bias all cols.
__global__ __launch_bounds__(256)
void dense1_kernel(const float* __restrict__ CI, const float* __restrict__ WP,
                   const float* __restrict__ Bias, float* __restrict__ H1)
{
    __shared__ float As[64 * 68];
    const int tid = threadIdx.x;
    const int tm = tid & 15;
    const int tn = tid >> 4;
    const int m0 = blockIdx.x * 64;

    float acc0[4][4], acc1[4][4];
    #pragma unroll
    for (int i = 0; i < 4; ++i)
        #pragma unroll
        for (int j = 0; j < 4; ++j) { acc0[i][j] = 0.f; acc1[i][j] = 0.f; }

    for (int i = tid; i < 64 * 64; i += 256) {
        int n = i >> 6, k = i & 63;
        int gn = m0 + n;
        As[k * 68 + n] = (gn < N_NODES) ? CI[(size_t)gn * 64 + k] : 0.f;
    }
    __syncthreads();
    #pragma unroll 4
    for (int k = 0; k < 64; ++k) {
        const float4 a  = *(const float4*)(As + k * 68 + 4 * tm);
        const float4 b0 = *(const float4*)(WP + k * 128 + 4 * tn);
        const float4 b1 = *(const float4*)(WP + k * 128 + 64 + 4 * tn);
        float av[4] = {a.x, a.y, a.z, a.w};
        float b0v[4] = {b0.x, b0.y, b0.z, b0.w};
        float b1v[4] = {b1.x, b1.y, b1.z, b1.w};
        #pragma unroll
        for (int i = 0; i < 4; ++i)
            #pragma unroll
            for (int j = 0; j < 4; ++j) {
                acc0[i][j] = fmaf(av[i], b0v[j], acc0[i][j]);
                acc1[i][j] = fmaf(av[i], b1v[j], acc1[i][j]);
            }
    }

    const float4 bias0 = *(const float4*)(Bias + 4 * tn);
    const float4 bias1 = *(const float4*)(Bias + 64 + 4 * tn);
    #pragma unroll
    for (int i = 0; i < 4; ++i) {
        int gm = m0 + 4 * tm + i;
        if (gm >= N_NODES) continue;
        *(float4*)(H1 + (size_t)gm * 128 + 4 * tn) =
            make_float4(acc0[i][0] + bias0.x, acc0[i][1] + bias0.y,
                        acc0[i][2] + bias0.z, acc0[i][3] + bias0.w);
        *(float4*)(H1 + (size_t)gm * 128 + 64 + 4 * tn) =
            make_float4(acc1[i][0] + bias1.x, acc1[i][1] + bias1.y,
                        acc1[i][2] + bias1.z, acc1[i][3] + bias1.w);
    }
}

// Layer 3: X=relu(h2) (N x 64), W1/W2 (64 x 32). Cols 0..31 -> HW1, 32..63 -> AGG+b.
__global__ __launch_bounds__(256)
void dense3_kernel(const float* __restrict__ X, const float* __restrict__ W1,
                   const float* __restrict__ W2, const float* __restrict__ Bias,
                   float* __restrict__ HW1, float* __restrict__ AGG)
{
    __shared__ float As[64 * 68];
    const int tid = threadIdx.x;
    const int tm = tid & 15;
    const int tn = tid >> 4;
    const int m0 = blockIdx.x * 64;

    float acc[4][4];
    #pragma unroll
    for (int i = 0; i < 4; ++i)
        #pragma unroll
        for (int j = 0; j < 4; ++j) acc[i][j] = 0.f;

    for (int i = tid; i < 64 * 64; i += 256) {
        int n = i >> 6, k = i & 63;
        int gn = m0 + n;
        float v = (gn < N_NODES) ? fmaxf(X[(size_t)gn * 64 + k], 0.f) : 0.f;
        As[k * 68 + n] = v;
    }
    __syncthreads();

    const bool w2half = (tn >= 8);
    const float* wptr = w2half ? (W2 + 4 * tn - 32) : (W1 + 4 * tn);
    #pragma unroll 4
    for (int k = 0; k < 64; ++k) {
        const float4 a = *(const float4*)(As + k * 68 + 4 * tm);
        const float4 b = *(const float4*)(wptr + k * 32);
        float av[4] = {a.x, a.y, a.z, a.w};
        float bv[4] = {b.x, b.y, b.z, b.w};
        #pragma unroll
        for (int i = 0; i < 4; ++i)
            #pragma unroll
            for (int j = 0; j < 4; ++j)
                acc[i][j] = fmaf(av[i], bv[j], acc[i][j]);
    }

    const int c = 4 * tn;
    float4 bias = make_float4(0.f, 0.f, 0.f, 0.f);
    if (w2half) bias = *(const float4*)(Bias + (c - 32));
    #pragma unroll
    for (int i = 0; i < 4; ++i) {
        int gm = m0 + 4 * tm + i;
        if (gm >= N_NODES) continue;
        float4 v = make_float4(acc[i][0] + bias.x, acc[i][1] + bias.y,
                               acc[i][2] + bias.z, acc[i][3] + bias.w);
        if (w2half)
            *(float4*)(AGG + (size_t)gm * 32 + (c - 32)) = v;
        else
            *(float4*)(HW1 + (size_t)gm * 32 + c) = v;
    }
}

// wpack[k][c]: k<30 -> w1_1[k][c]; 32<=k<62 -> w2_1[k-32][c]; else 0.
__global__ __launch_bounds__(256)
void wpack_kernel(const float* __restrict__ W1, const float* __restrict__ W2,
                  float* __restrict__ WP)
{
    int idx = blockIdx.x * 256 + threadIdx.x;   // 8192 total
    if (idx >= 64 * 128) return;
    int k = idx >> 7, c = idx & 127;
    float w = 0.f;
    if (k < 30) w = W1[k * 128 + c];
    else if (k >= 32 && k < 62) w = W2[(k - 32) * 128 + c];
    WP[idx] = w;
}

// ---------------------------------------------------------------------------
// CSR build, pass 1a: per-block coarse histogram (dst>>8) into LDS, then
// ghist[bucket*256 + block] (bucket-major for the scan).
// ---------------------------------------------------------------------------
__global__ __launch_bounds__(256)
void c_hist(const int* __restrict__ ER, int* __restrict__ ghist)
{
    __shared__ int h[NCB];
    int t = threadIdx.x, blk = blockIdx.x;
    for (int i = t; i < NCB; i += 256) h[i] = 0;
    __syncthreads();
    int lo = blk * CHUNK, hi = lo + CHUNK;
    for (int e = lo + t; e < hi; e += 256) atomicAdd(&h[ER[e] >> 8], 1);
    __syncthreads();
    for (int i = t; i < NCB; i += 256) ghist[i * 256 + blk] = h[i];
}

// --- 3-phase exclusive scan of ghist (GH_LEN entries) in place -> gofs ---
__global__ __launch_bounds__(256)
void g_blocksum(const int* __restrict__ gh, int* __restrict__ bsum)
{
    __shared__ int red[4];
    int i = blockIdx.x * 256 + threadIdx.x;   // GH_LEN % 256 == 0
    int v = gh[i];
    #pragma unroll
    for (int off = 32; off; off >>= 1) v += __shfl_down(v, off, 64);
    if ((threadIdx.x & 63) == 0) red[threadIdx.x >> 6] = v;
    __syncthreads();
    if (threadIdx.x == 0) bsum[blockIdx.x] = red[0] + red[1] + red[2] + red[3];
}

__global__ __launch_bounds__(256)
void g_bscan(int* __restrict__ bsum)          // exclusive scan of NCB entries
{
    __shared__ int s[256];
    int t = threadIdx.x;
    int v = (t < NCB) ? bsum[t] : 0;
    s[t] = v;
    __syncthreads();
    for (int off = 1; off < 256; off <<= 1) {
        int u = (t >= off) ? s[t - off] : 0;
        __syncthreads();
        s[t] += u;
        __syncthreads();
    }
    if (t < NCB) bsum[t] = s[t] - v;
}

__global__ __launch_bounds__(256)
void g_apply(int* __restrict__ gh, const int* __restrict__ bsum)
{
    __shared__ int s[256];
    int t = threadIdx.x;
    int i = blockIdx.x * 256 + t;
    int v = gh[i];
    s[t] = v;
    __syncthreads();
    for (int off = 1; off < 256; off <<= 1) {
        int u = (t >= off) ? s[t - off] : 0;
        __syncthreads();
        s[t] += u;
        __syncthreads();
    }
    gh[i] = s[t] - v + bsum[blockIdx.x];      // exclusive, in place
}

// ---------------------------------------------------------------------------
// CSR build, pass 1b: coarse scatter into per-block contiguous runs.
// Record: x = src | ((dst&255)<<16), y = w bits.
// ---------------------------------------------------------------------------
__global__ __launch_bounds__(256)
void c_scatter(const int* __restrict__ ER, const int* __restrict__ EC,
               const float* __restrict__ EW, const int* __restrict__ gofs,
               int2* __restrict__ tmp)
{
    __shared__ int cur[NCB];
    int t = threadIdx.x, blk = blockIdx.x;
    for (int i = t; i < NCB; i += 256) cur[i] = gofs[i * 256 + blk];
    __syncthreads();
    int lo = blk * CHUNK, hi = lo + CHUNK;
    for (int e = lo + t; e < hi; e += 256) {
        int d = ER[e];
        int pos = atomicAdd(&cur[d >> 8], 1);
        tmp[pos] = make_int2(EC[e] | ((d & 255) << 16), __float_as_int(EW[e]));
    }
}

// ---------------------------------------------------------------------------
// CSR build, pass 2: per-bucket counting sort by dst&255; emits final packed
// (src,w) dest-sorted AND rowptr.
// ---------------------------------------------------------------------------
__global__ __launch_bounds__(256)
void bsort(const int2* __restrict__ tmp, const int* __restrict__ gofs,
           int2* __restrict__ packed, int* __restrict__ rowptr)
{
    __shared__ int hist[256];
    __shared__ int s[256];
    __shared__ int cur[256];
    int g = blockIdx.x, t = threadIdx.x;
    int base = gofs[g * 256];
    int end  = (g == NCB - 1) ? N_EDGES : gofs[(g + 1) * 256];
    hist[t] = 0;
    __syncthreads();
    for (int j = base + t; j < end; j += 256)
        atomicAdd(&hist[(tmp[j].x >> 16) & 255], 1);
    __syncthreads();
    int v = hist[t];
    s[t] = v;
    __syncthreads();
    for (int off = 1; off < 256; off <<= 1) {
        int u = (t >= off) ? s[t - off] : 0;
        __syncthreads();
        s[t] += u;
        __syncthreads();
    }
    int excl = s[t] - v;
    int n = g * 256 + t;
    if (n < N_NODES) rowptr[n] = base + excl;
    if (g == NCB - 1 && t == 0) rowptr[N_NODES] = N_EDGES;
    cur[t] = base + excl;
    __syncthreads();
    for (int j = base + t; j < end; j += 256) {
        int2 r = tmp[j];
        int pos = atomicAdd(&cur[(r.x >> 16) & 255], 1);
        packed[pos] = make_int2(r.x & 0xFFFF, r.y);
    }
}

// ---------------------------------------------------------------------------
// pad_kernel: XP[n][c] = (c<30) ? x[n][c] : 0 ; CI[n][32+c] = same
// ---------------------------------------------------------------------------
__global__ __launch_bounds__(256)
void pad_kernel(const float* __restrict__ X, float* __restrict__ XP,
                float* __restrict__ CI)
{
    int idx = blockIdx.x * 256 + threadIdx.x;
    int n = idx >> 5;
    int c = idx & 31;
    if (n >= N_NODES) return;
    float v = (c < 30) ? X[n * 30 + c] : 0.f;
    XP[(size_t)n * 32 + c] = v;
    CI[(size_t)n * 64 + 32 + c] = v;
}

// ---------------------------------------------------------------------------
// aggx_kernel: CI[n][0..31] = sum_j w_j * XP[src_j][0..31]  (A @ X)
// ---------------------------------------------------------------------------
__global__ __launch_bounds__(256)
void aggx_kernel(const float* __restrict__ XP, const int* __restrict__ rowptr,
                 const int2* __restrict__ packed, float* __restrict__ CI)
{
    int tid = threadIdx.x;
    int local = tid >> 3;
    int q = tid & 7;
    int n = blockIdx.x * 32 + local;
    if (n >= N_NODES) return;
    int r0 = rowptr[n], r1 = rowptr[n + 1];
    float4 acc = make_float4(0.f, 0.f, 0.f, 0.f);
    for (int j = r0; j < r1; ++j) {
        int2 r = packed[j];
        float w = __int_as_float(r.y);
        const float4 h = *(const float4*)(XP + (size_t)r.x * 32 + q * 4);
        acc.x = fmaf(w, h.x, acc.x);
        acc.y = fmaf(w, h.y, acc.y);
        acc.z = fmaf(w, h.z, acc.z);
        acc.w = fmaf(w, h.w, acc.w);
    }
    *(float4*)(CI + (size_t)n * 64 + q * 4) = acc;
}

// ---------------------------------------------------------------------------
// Atomic-free SpMM (layers 2,3)
// ---------------------------------------------------------------------------
template<int FOUT>
__global__ __launch_bounds__(256)
void spmm_kernel(const float* __restrict__ HW1, const int* __restrict__ rowptr,
                 const int2* __restrict__ packed, float* __restrict__ AGG)
{
    constexpr int T = FOUT / 4;
    constexpr int NPB = 256 / T;
    int tid = threadIdx.x;
    int local = tid / T;
    int q = tid % T;
    int n = blockIdx.x * NPB + local;
    if (n >= N_NODES) return;
    int r0 = rowptr[n], r1 = rowptr[n + 1];
    float4 acc = *(const float4*)(AGG + (size_t)n * FOUT + q * 4);
    for (int j = r0; j < r1; ++j) {
        int2 r = packed[j];
        float w = __int_as_float(r.y);
        const float4 h = *(const float4*)(HW1 + (size_t)r.x * FOUT + q * 4);
        acc.x = fmaf(w, h.x, acc.x);
        acc.y = fmaf(w, h.y, acc.y);
        acc.z = fmaf(w, h.z, acc.z);
        acc.w = fmaf(w, h.w, acc.w);
    }
    *(float4*)(AGG + (size_t)n * FOUT + q * 4) = acc;
}

// ---------------------------------------------------------------------------
// Graph boundaries from sorted seg
// ---------------------------------------------------------------------------
__global__ __launch_bounds__(256)
void bounds_kernel(const int* __restrict__ SEG, int* __restrict__ start)
{
    int n = blockIdx.x * 256 + threadIdx.x;
    if (n >= N_NODES) return;
    int g = SEG[n];
    int gprev = (n == 0) ? -1 : SEG[n - 1];
    for (int gg = gprev + 1; gg <= g; ++gg) start[gg] = n;
    if (n == N_NODES - 1)
        for (int gg = g + 1; gg <= N_GRAPHS; ++gg) start[gg] = N_NODES;
}

// ---------------------------------------------------------------------------
// Atomic-free pool
// ---------------------------------------------------------------------------
__global__ __launch_bounds__(256)
void pool_kernel(const float* __restrict__ H, const int* __restrict__ start,
                 float* __restrict__ POOLED)
{
    __shared__ float red[8][33];
    int g = blockIdx.x;
    int s = start[g], e = start[g + 1];
    int q = threadIdx.x & 31;
    int lane = threadIdx.x >> 5;
    float acc = 0.f;
    for (int n = s + lane; n < e; n += 8)
        acc += fmaxf(H[(size_t)n * 32 + q], 0.f);
    red[lane][q] = acc;
    __syncthreads();
    if (threadIdx.x < 32) {
        float v = 0.f;
        #pragma unroll
        for (int i = 0; i < 8; ++i) v += red[i][q];
        float inv = (e > s) ? 1.0f / (float)(e - s) : 1.0f;
        POOLED[g * 32 + q] = v * inv;
    }
}

// ---------------------------------------------------------------------------
// Head
// ---------------------------------------------------------------------------
__global__ __launch_bounds__(256)
void head_kernel(const float* __restrict__ POOLED, const float* __restrict__ WD,
                 const float* __restrict__ BD, float* __restrict__ OUT)
{
    int g = threadIdx.x;
    float l0 = BD[0], l1 = BD[1];
    #pragma unroll
    for (int k = 0; k < 32; ++k) {
        float p = POOLED[g * 32 + k];
        l0 = fmaf(p, WD[k * 2 + 0], l0);
        l1 = fmaf(p, WD[k * 2 + 1], l1);
    }
    float m = fmaxf(l0, l1);
    float e0 = expf(l0 - m), e1 = expf(l1 - m);
    float s = 1.0f / (e0 + e1);
    OUT[g * 2 + 0] = e0 * s;
    OUT[g * 2 + 1] = e1 * s;
}

extern "C" void kernel_launch(void* const* d_in, const int* in_sizes, int n_in,
                              void* d_out, int out_size, void* d_ws, size_t ws_size,
                              hipStream_t stream)
{
    const float* x    = (const float*)d_in[0];
    const float* ew   = (const float*)d_in[1];
    const int*   er   = (const int*)d_in[2];
    const int*   ec   = (const int*)d_in[3];
    const int*   seg  = (const int*)d_in[4];
    const float* w1_1 = (const float*)d_in[5];
    const float* w2_1 = (const float*)d_in[6];
    const float* b_1  = (const float*)d_in[7];
    const float* w1_2 = (const float*)d_in[8];
    const float* w2_2 = (const float*)d_in[9];
    const float* b_2  = (const float*)d_in[10];
    const float* w1_3 = (const float*)d_in[11];
    const float* w2_3 = (const float*)d_in[12];
    const float* b_3  = (const float*)d_in[13];
    const float* wd   = (const float*)d_in[14];
    const float* bd   = (const float*)d_in[15];

    float* ws = (float*)d_ws;
    // Phase 1 (layer 1): CI 0..3.2M, XP 3.2..4.8M, B(h1) 6.4..12.8M
    float* CI     = ws;                        // N x 64
    float* XP     = ws + 3200000;              // N x 32
    float* B      = ws + 6400000;              // N x 128 (h1)
    int2*  tmp    = (int2*)(ws + 6400000);     // E x int2 (CSR build; dead before h1)
    // Phase 2: A 0.., A2 3.2M..; Phase 3: H3 6.4M.., B2 8.0M..
    float* A      = ws;                        // N x 64  (HW1_2)
    float* A2     = ws + 3200000;              // N x 64  (h2)
    float* H3     = ws + 6400000;              // N x 32  (HW1_3)
    float* B2     = ws + 8000000;              // N x 32  (h3)
    int*   IW     = (int*)d_ws;
    int2*  packed = (int2*)(IW + 12800000);    // E x {src, w}  (6.4 MB)
    int*   rowptr = IW + 14400000;             // N+1
    int*   gofs   = IW + 14460000;             // GH_LEN (ghist -> scanned in place)
    int*   bsum   = IW + 14515000;             // NCB
    int*   start  = IW + 14520000;             // G+1
    float* POOLED = ws + 14525000;             // 256 x 32
    float* WP     = ws + 14540000;             // 64 x 128 packed layer-1 weights

    dim3 blk(256);
    const int MB = (N_NODES + 63) / 64;        // 782

    // ---- CSR build: locality-preserving two-pass counting sort ----
    c_hist<<<dim3(256), blk, 0, stream>>>(er, gofs);
    g_blocksum<<<dim3(GH_LEN / 256), blk, 0, stream>>>(gofs, bsum);
    g_bscan<<<dim3(1), blk, 0, stream>>>(bsum);
    g_apply<<<dim3(GH_LEN / 256), blk, 0, stream>>>(gofs, bsum);
    c_scatter<<<dim3(256), blk, 0, stream>>>(er, ec, ew, gofs, tmp);
    bsort<<<dim3(NCB), blk, 0, stream>>>(tmp, gofs, packed, rowptr);
    bounds_kernel<<<dim3((N_NODES + 255) / 256), blk, 0, stream>>>(seg, start);
    wpack_kernel<<<dim3(32), blk, 0, stream>>>(w1_1, w2_1, WP);

    // Layer 1 (pre-aggregation form): CI = [A@X | X], h1 = CI @ wpack + b
    pad_kernel<<<dim3((N_NODES * 32 + 255) / 256), blk, 0, stream>>>(x, XP, CI);
    aggx_kernel<<<dim3((N_NODES + 31) / 32), blk, 0, stream>>>(XP, rowptr, packed, CI);
    dense1_kernel<<<dim3(MB), blk, 0, stream>>>(CI, WP, b_1, B);
    // Layer 2: relu(h1)(128) -> 64
    dense2_kernel<<<dim3(MB), blk, 0, stream>>>(B, w1_2, w2_2, b_2, A, A2);
    spmm_kernel<64><<<dim3((N_NODES + 15) / 16), blk, 0, stream>>>(A, rowptr, packed, A2);
    // Layer 3: relu(h2)(64) -> 32
    dense3_kernel<<<dim3(MB), blk, 0, stream>>>(A2, w1_3, w2_3, b_3, H3, B2);
    spmm_kernel<32><<<dim3((N_NODES + 31) / 32), blk, 0, stream>>>(H3, rowptr, packed, B2);

    // Pool + head (atomic-free)
    pool_kernel<<<dim3(N_GRAPHS), blk, 0, stream>>>(B2, start, POOLED);
    head_kernel<<<dim3(1), blk, 0, stream>>>(POOLED, wd, bd, (float*)d_out);
}

// Round 9
// 276.881 us; speedup vs baseline: 1.1373x; 1.1373x over previous
//
#include <hip/hip_runtime.h>

#define N_NODES 50000
#define N_EDGES 800000
#define N_GRAPHS 256
#define NCB 196        // coarse buckets = ceil(50000/256), dst>>8
#define CHUNK 3125     // edges per block in coarse passes (256 blocks)
#define GH_LEN (NCB * 256)   // 50176

// ---------------------------------------------------------------------------
// Dense GEMM v3: lane = row (64 rows/block), wave owns 16 output columns,
// acc[16]/lane. A staged [m][K+4] in LDS (stride = 4 mod 32 -> conflict-free
// ds_read_b128, each A value read once per wave). B fragments are
// WAVE-UNIFORM -> scalar loads via readfirstlane'd pointer (no vmcnt, no LDS
// in the B path). Per 4-k step: 1 ds_read_b128 + 64 FMA -> VALU-bound.
// ---------------------------------------------------------------------------
template<int K, int NW, bool RELU>
__device__ __forceinline__ void dense_core(
    const float* __restrict__ X,      // N x K input (row-major)
    const float* __restrict__ Wcol,   // W + wave's column offset (uniform)
    int wstride,                      // W row stride
    const float* __restrict__ Bcol,   // Bias + col offset (uniform) or nullptr
    float* __restrict__ Ocol,         // OUT + col offset (uniform)
    int ostride)                      // OUT row stride
{
    constexpr int KP = K + 4;
    __shared__ float As[64 * KP];
    const int tid = threadIdx.x;
    const int m0 = blockIdx.x * 64;
    constexpr int T = NW * 64;

    // stage A tile (64 x K), coalesced, optional relu
    for (int i = tid * 4; i < 64 * K; i += T * 4) {
        int row = i / K;
        int col = i % K;
        int gm = m0 + row;
        float4 v = make_float4(0.f, 0.f, 0.f, 0.f);
        if (gm < N_NODES) v = *(const float4*)(X + (size_t)gm * K + col);
        if (RELU) {
            v.x = fmaxf(v.x, 0.f); v.y = fmaxf(v.y, 0.f);
            v.z = fmaxf(v.z, 0.f); v.w = fmaxf(v.w, 0.f);
        }
        *(float4*)(As + row * KP + col) = v;
    }
    __syncthreads();

    const int lane = tid & 63;
    float acc[16];
    #pragma unroll
    for (int j = 0; j < 16; ++j) acc[j] = 0.f;
    const float* arow = As + lane * KP;

    for (int k = 0; k < K; k += 4) {
        float4 a = *(const float4*)(arow + k);
        float av[4] = {a.x, a.y, a.z, a.w};
        #pragma unroll
        for (int kk = 0; kk < 4; ++kk) {
            const float* wr = Wcol + (k + kk) * wstride;   // uniform address
            #pragma unroll
            for (int j = 0; j < 16; ++j)
                acc[j] = fmaf(av[kk], wr[j], acc[j]);
        }
    }

    int gm = m0 + lane;
    if (gm < N_NODES) {
        float* orow = Ocol + (size_t)gm * ostride;
        #pragma unroll
        for (int j4 = 0; j4 < 4; ++j4) {
            float4 v = make_float4(acc[j4*4+0], acc[j4*4+1], acc[j4*4+2], acc[j4*4+3]);
            if (Bcol) {
                float4 b = *(const float4*)(Bcol + j4 * 4);
                v.x += b.x; v.y += b.y; v.z += b.z; v.w += b.w;
            }
            *(float4*)(orow + j4 * 4) = v;
        }
    }
}

// Layer 1: CI (N x 64) @ WP (64 x 128) + b -> H1 (N x 128). 8 waves.
__global__ __launch_bounds__(512)
void dense1_kernel(const float* __restrict__ CI, const float* __restrict__ WP,
                   const float* __restrict__ Bias, float* __restrict__ H1)
{
    int wid = __builtin_amdgcn_readfirstlane(threadIdx.x >> 6);
    dense_core<64, 8, false>(CI, WP + wid * 16, 128, Bias + wid * 16,
                             H1 + wid * 16, 128);
}

// Layer 2: relu(h1) (N x 128); waves 0-3 -> W1/HW1, 4-7 -> W2/AGG+bias.
__global__ __launch_bounds__(512)
void dense2_kernel(const float* __restrict__ X, const float* __restrict__ W1,
                   const float* __restrict__ W2, const float* __restrict__ Bias,
                   float* __restrict__ HW1, float* __restrict__ AGG)
{
    int wid = __builtin_amdgcn_readfirstlane(threadIdx.x >> 6);
    const float* Wc; const float* Bc; float* Oc;
    if (wid < 4) { Wc = W1 + wid * 16;       Bc = nullptr;            Oc = HW1 + wid * 16; }
    else         { Wc = W2 + (wid - 4) * 16; Bc = Bias + (wid-4)*16;  Oc = AGG + (wid - 4) * 16; }
    dense_core<128, 8, true>(X, Wc, 64, Bc, Oc, 64);
}

// Layer 3: relu(h2) (N x 64); waves 0-1 -> W1/HW1, 2-3 -> W2/AGG+bias.
__global__ __launch_bounds__(256)
void dense3_kernel(const float* __restrict__ X, const float* __restrict__ W1,
                   const float* __restrict__ W2, const float* __restrict__ Bias,
                   float* __restrict__ HW1, float* __restrict__ AGG)
{
    int wid = __builtin_amdgcn_readfirstlane(threadIdx.x >> 6);
    const float* Wc; const float* Bc; float* Oc;
    if (wid < 2) { Wc = W1 + wid * 16;       Bc = nullptr;            Oc = HW1 + wid * 16; }
    else         { Wc = W2 + (wid - 2) * 16; Bc = Bias + (wid-2)*16;  Oc = AGG + (wid - 2) * 16; }
    dense_core<64, 4, true>(X, Wc, 32, Bc, Oc, 32);
}

// wpack[k][c]: k<30 -> w1_1[k][c]; 32<=k<62 -> w2_1[k-32][c]; else 0.
__global__ __launch_bounds__(256)
void wpack_kernel(const float* __restrict__ W1, const float* __restrict__ W2,
                  float* __restrict__ WP)
{
    int idx = blockIdx.x * 256 + threadIdx.x;   // 8192 total
    if (idx >= 64 * 128) return;
    int k = idx >> 7, c = idx & 127;
    float w = 0.f;
    if (k < 30) w = W1[k * 128 + c];
    else if (k >= 32 && k < 62) w = W2[(k - 32) * 128 + c];
    WP[idx] = w;
}

// ---------------------------------------------------------------------------
// CSR build, pass 1a: per-block coarse histogram (dst>>8), bucket-major out.
// ---------------------------------------------------------------------------
__global__ __launch_bounds__(256)
void c_hist(const int* __restrict__ ER, int* __restrict__ ghist)
{
    __shared__ int h[NCB];
    int t = threadIdx.x, blk = blockIdx.x;
    for (int i = t; i < NCB; i += 256) h[i] = 0;
    __syncthreads();
    int lo = blk * CHUNK, hi = lo + CHUNK;
    for (int e = lo + t; e < hi; e += 256) atomicAdd(&h[ER[e] >> 8], 1);
    __syncthreads();
    for (int i = t; i < NCB; i += 256) ghist[i * 256 + blk] = h[i];
}

// --- 3-phase exclusive scan of ghist (GH_LEN entries) in place -> gofs ---
__global__ __launch_bounds__(256)
void g_blocksum(const int* __restrict__ gh, int* __restrict__ bsum)
{
    __shared__ int red[4];
    int i = blockIdx.x * 256 + threadIdx.x;   // GH_LEN % 256 == 0
    int v = gh[i];
    #pragma unroll
    for (int off = 32; off; off >>= 1) v += __shfl_down(v, off, 64);
    if ((threadIdx.x & 63) == 0) red[threadIdx.x >> 6] = v;
    __syncthreads();
    if (threadIdx.x == 0) bsum[blockIdx.x] = red[0] + red[1] + red[2] + red[3];
}

__global__ __launch_bounds__(256)
void g_bscan(int* __restrict__ bsum)          // exclusive scan of NCB entries
{
    __shared__ int s[256];
    int t = threadIdx.x;
    int v = (t < NCB) ? bsum[t] : 0;
    s[t] = v;
    __syncthreads();
    for (int off = 1; off < 256; off <<= 1) {
        int u = (t >= off) ? s[t - off] : 0;
        __syncthreads();
        s[t] += u;
        __syncthreads();
    }
    if (t < NCB) bsum[t] = s[t] - v;
}

__global__ __launch_bounds__(256)
void g_apply(int* __restrict__ gh, const int* __restrict__ bsum)
{
    __shared__ int s[256];
    int t = threadIdx.x;
    int i = blockIdx.x * 256 + t;
    int v = gh[i];
    s[t] = v;
    __syncthreads();
    for (int off = 1; off < 256; off <<= 1) {
        int u = (t >= off) ? s[t - off] : 0;
        __syncthreads();
        s[t] += u;
        __syncthreads();
    }
    gh[i] = s[t] - v + bsum[blockIdx.x];      // exclusive, in place
}

// ---------------------------------------------------------------------------
// CSR build, pass 1b: coarse scatter into per-block contiguous runs.
// Record: x = src | ((dst&255)<<16), y = w bits.
// ---------------------------------------------------------------------------
__global__ __launch_bounds__(256)
void c_scatter(const int* __restrict__ ER, const int* __restrict__ EC,
               const float* __restrict__ EW, const int* __restrict__ gofs,
               int2* __restrict__ tmp)
{
    __shared__ int cur[NCB];
    int t = threadIdx.x, blk = blockIdx.x;
    for (int i = t; i < NCB; i += 256) cur[i] = gofs[i * 256 + blk];
    __syncthreads();
    int lo = blk * CHUNK, hi = lo + CHUNK;
    for (int e = lo + t; e < hi; e += 256) {
        int d = ER[e];
        int pos = atomicAdd(&cur[d >> 8], 1);
        tmp[pos] = make_int2(EC[e] | ((d & 255) << 16), __float_as_int(EW[e]));
    }
}

// ---------------------------------------------------------------------------
// CSR build, pass 2: per-bucket counting sort by dst&255; emits final packed
// (src,w) dest-sorted AND rowptr.
// ---------------------------------------------------------------------------
__global__ __launch_bounds__(256)
void bsort(const int2* __restrict__ tmp, const int* __restrict__ gofs,
           int2* __restrict__ packed, int* __restrict__ rowptr)
{
    __shared__ int hist[256];
    __shared__ int s[256];
    __shared__ int cur[256];
    int g = blockIdx.x, t = threadIdx.x;
    int base = gofs[g * 256];
    int end  = (g == NCB - 1) ? N_EDGES : gofs[(g + 1) * 256];
    hist[t] = 0;
    __syncthreads();
    for (int j = base + t; j < end; j += 256)
        atomicAdd(&hist[(tmp[j].x >> 16) & 255], 1);
    __syncthreads();
    int v = hist[t];
    s[t] = v;
    __syncthreads();
    for (int off = 1; off < 256; off <<= 1) {
        int u = (t >= off) ? s[t - off] : 0;
        __syncthreads();
        s[t] += u;
        __syncthreads();
    }
    int excl = s[t] - v;
    int n = g * 256 + t;
    if (n < N_NODES) rowptr[n] = base + excl;
    if (g == NCB - 1 && t == 0) rowptr[N_NODES] = N_EDGES;
    cur[t] = base + excl;
    __syncthreads();
    for (int j = base + t; j < end; j += 256) {
        int2 r = tmp[j];
        int pos = atomicAdd(&cur[(r.x >> 16) & 255], 1);
        packed[pos] = make_int2(r.x & 0xFFFF, r.y);
    }
}

// ---------------------------------------------------------------------------
// pad_kernel: XP[n][c] = (c<30) ? x[n][c] : 0 ; CI[n][32+c] = same
// ---------------------------------------------------------------------------
__global__ __launch_bounds__(256)
void pad_kernel(const float* __restrict__ X, float* __restrict__ XP,
                float* __restrict__ CI)
{
    int idx = blockIdx.x * 256 + threadIdx.x;
    int n = idx >> 5;
    int c = idx & 31;
    if (n >= N_NODES) return;
    float v = (c < 30) ? X[n * 30 + c] : 0.f;
    XP[(size_t)n * 32 + c] = v;
    CI[(size_t)n * 64 + 32 + c] = v;
}

// ---------------------------------------------------------------------------
// aggx_kernel: CI[n][0..31] = sum_j w_j * XP[src_j][0..31]  (A @ X)
// ---------------------------------------------------------------------------
__global__ __launch_bounds__(256)
void aggx_kernel(const float* __restrict__ XP, const int* __restrict__ rowptr,
                 const int2* __restrict__ packed, float* __restrict__ CI)
{
    int tid = threadIdx.x;
    int local = tid >> 3;
    int q = tid & 7;
    int n = blockIdx.x * 32 + local;
    if (n >= N_NODES) return;
    int r0 = rowptr[n], r1 = rowptr[n + 1];
    float4 acc = make_float4(0.f, 0.f, 0.f, 0.f);
    for (int j = r0; j < r1; ++j) {
        int2 r = packed[j];
        float w = __int_as_float(r.y);
        const float4 h = *(const float4*)(XP + (size_t)r.x * 32 + q * 4);
        acc.x = fmaf(w, h.x, acc.x);
        acc.y = fmaf(w, h.y, acc.y);
        acc.z = fmaf(w, h.z, acc.z);
        acc.w = fmaf(w, h.w, acc.w);
    }
    *(float4*)(CI + (size_t)n * 64 + q * 4) = acc;
}

// ---------------------------------------------------------------------------
// Atomic-free SpMM (layers 2,3)
// ---------------------------------------------------------------------------
template<int FOUT>
__global__ __launch_bounds__(256)
void spmm_kernel(const float* __restrict__ HW1, const int* __restrict__ rowptr,
                 const int2* __restrict__ packed, float* __restrict__ AGG)
{
    constexpr int T = FOUT / 4;
    constexpr int NPB = 256 / T;
    int tid = threadIdx.x;
    int local = tid / T;
    int q = tid % T;
    int n = blockIdx.x * NPB + local;
    if (n >= N_NODES) return;
    int r0 = rowptr[n], r1 = rowptr[n + 1];
    float4 acc = *(const float4*)(AGG + (size_t)n * FOUT + q * 4);
    for (int j = r0; j < r1; ++j) {
        int2 r = packed[j];
        float w = __int_as_float(r.y);
        const float4 h = *(const float4*)(HW1 + (size_t)r.x * FOUT + q * 4);
        acc.x = fmaf(w, h.x, acc.x);
        acc.y = fmaf(w, h.y, acc.y);
        acc.z = fmaf(w, h.z, acc.z);
        acc.w = fmaf(w, h.w, acc.w);
    }
    *(float4*)(AGG + (size_t)n * FOUT + q * 4) = acc;
}

// ---------------------------------------------------------------------------
// Graph boundaries from sorted seg
// ---------------------------------------------------------------------------
__global__ __launch_bounds__(256)
void bounds_kernel(const int* __restrict__ SEG, int* __restrict__ start)
{
    int n = blockIdx.x * 256 + threadIdx.x;
    if (n >= N_NODES) return;
    int g = SEG[n];
    int gprev = (n == 0) ? -1 : SEG[n - 1];
    for (int gg = gprev + 1; gg <= g; ++gg) start[gg] = n;
    if (n == N_NODES - 1)
        for (int gg = g + 1; gg <= N_GRAPHS; ++gg) start[gg] = N_NODES;
}

// ---------------------------------------------------------------------------
// Atomic-free pool
// ---------------------------------------------------------------------------
__global__ __launch_bounds__(256)
void pool_kernel(const float* __restrict__ H, const int* __restrict__ start,
                 float* __restrict__ POOLED)
{
    __shared__ float red[8][33];
    int g = blockIdx.x;
    int s = start[g], e = start[g + 1];
    int q = threadIdx.x & 31;
    int lane = threadIdx.x >> 5;
    float acc = 0.f;
    for (int n = s + lane; n < e; n += 8)
        acc += fmaxf(H[(size_t)n * 32 + q], 0.f);
    red[lane][q] = acc;
    __syncthreads();
    if (threadIdx.x < 32) {
        float v = 0.f;
        #pragma unroll
        for (int i = 0; i < 8; ++i) v += red[i][q];
        float inv = (e > s) ? 1.0f / (float)(e - s) : 1.0f;
        POOLED[g * 32 + q] = v * inv;
    }
}

// ---------------------------------------------------------------------------
// Head
// ---------------------------------------------------------------------------
__global__ __launch_bounds__(256)
void head_kernel(const float* __restrict__ POOLED, const float* __restrict__ WD,
                 const float* __restrict__ BD, float* __restrict__ OUT)
{
    int g = threadIdx.x;
    float l0 = BD[0], l1 = BD[1];
    #pragma unroll
    for (int k = 0; k < 32; ++k) {
        float p = POOLED[g * 32 + k];
        l0 = fmaf(p, WD[k * 2 + 0], l0);
        l1 = fmaf(p, WD[k * 2 + 1], l1);
    }
    float m = fmaxf(l0, l1);
    float e0 = expf(l0 - m), e1 = expf(l1 - m);
    float s = 1.0f / (e0 + e1);
    OUT[g * 2 + 0] = e0 * s;
    OUT[g * 2 + 1] = e1 * s;
}

extern "C" void kernel_launch(void* const* d_in, const int* in_sizes, int n_in,
                              void* d_out, int out_size, void* d_ws, size_t ws_size,
                              hipStream_t stream)
{
    const float* x    = (const float*)d_in[0];
    const float* ew   = (const float*)d_in[1];
    const int*   er   = (const int*)d_in[2];
    const int*   ec   = (const int*)d_in[3];
    const int*   seg  = (const int*)d_in[4];
    const float* w1_1 = (const float*)d_in[5];
    const float* w2_1 = (const float*)d_in[6];
    const float* b_1  = (const float*)d_in[7];
    const float* w1_2 = (const float*)d_in[8];
    const float* w2_2 = (const float*)d_in[9];
    const float* b_2  = (const float*)d_in[10];
    const float* w1_3 = (const float*)d_in[11];
    const float* w2_3 = (const float*)d_in[12];
    const float* b_3  = (const float*)d_in[13];
    const float* wd   = (const float*)d_in[14];
    const float* bd   = (const float*)d_in[15];

    float* ws = (float*)d_ws;
    // Phase 1 (layer 1): CI 0..3.2M, XP 3.2..4.8M, B(h1) 6.4..12.8M
    float* CI     = ws;                        // N x 64
    float* XP     = ws + 3200000;              // N x 32
    float* B      = ws + 6400000;              // N x 128 (h1)
    int2*  tmp    = (int2*)(ws + 6400000);     // E x int2 (CSR build; dead before h1)
    // Phase 2: A 0.., A2 3.2M..; Phase 3: H3 6.4M.., B2 8.0M..
    float* A      = ws;                        // N x 64  (HW1_2)
    float* A2     = ws + 3200000;              // N x 64  (h2)
    float* H3     = ws + 6400000;              // N x 32  (HW1_3)
    float* B2     = ws + 8000000;              // N x 32  (h3)
    int*   IW     = (int*)d_ws;
    int2*  packed = (int2*)(IW + 12800000);    // E x {src, w}  (6.4 MB)
    int*   rowptr = IW + 14400000;             // N+1
    int*   gofs   = IW + 14460000;             // GH_LEN (ghist -> scanned in place)
    int*   bsum   = IW + 14515000;             // NCB
    int*   start  = IW + 14520000;             // G+1
    float* POOLED = ws + 14525000;             // 256 x 32
    float* WP     = ws + 14540000;             // 64 x 128 packed layer-1 weights

    dim3 blk(256);
    const int MB = (N_NODES + 63) / 64;        // 782

    // ---- CSR build: locality-preserving two-pass counting sort ----
    c_hist<<<dim3(256), blk, 0, stream>>>(er, gofs);
    g_blocksum<<<dim3(GH_LEN / 256), blk, 0, stream>>>(gofs, bsum);
    g_bscan<<<dim3(1), blk, 0, stream>>>(bsum);
    g_apply<<<dim3(GH_LEN / 256), blk, 0, stream>>>(gofs, bsum);
    c_scatter<<<dim3(256), blk, 0, stream>>>(er, ec, ew, gofs, tmp);
    bsort<<<dim3(NCB), blk, 0, stream>>>(tmp, gofs, packed, rowptr);
    bounds_kernel<<<dim3((N_NODES + 255) / 256), blk, 0, stream>>>(seg, start);
    wpack_kernel<<<dim3(32), blk, 0, stream>>>(w1_1, w2_1, WP);

    // Layer 1 (pre-aggregation form): CI = [A@X | X], h1 = CI @ wpack + b
    pad_kernel<<<dim3((N_NODES * 32 + 255) / 256), blk, 0, stream>>>(x, XP, CI);
    aggx_kernel<<<dim3((N_NODES + 31) / 32), blk, 0, stream>>>(XP, rowptr, packed, CI);
    dense1_kernel<<<dim3(MB), dim3(512), 0, stream>>>(CI, WP, b_1, B);
    // Layer 2: relu(h1)(128) -> 64
    dense2_kernel<<<dim3(MB), dim3(512), 0, stream>>>(B, w1_2, w2_2, b_2, A, A2);
    spmm_kernel<64><<<dim3((N_NODES + 15) / 16), blk, 0, stream>>>(A, rowptr, packed, A2);
    // Layer 3: relu(h2)(64) -> 32
    dense3_kernel<<<dim3(MB), blk, 0, stream>>>(A2, w1_3, w2_3, b_3, H3, B2);
    spmm_kernel<32><<<dim3((N_NODES + 31) / 32), blk, 0, stream>>>(H3, rowptr, packed, B2);

    // Pool + head (atomic-free)
    pool_kernel<<<dim3(N_GRAPHS), blk, 0, stream>>>(B2, start, POOLED);
    head_kernel<<<dim3(1), blk, 0, stream>>>(POOLED, wd, bd, (float*)d_out);
}

// Round 10
// 262.128 us; speedup vs baseline: 1.2013x; 1.0563x over previous
//
#include <hip/hip_runtime.h>
#include <hip/hip_fp16.h>

#define N_NODES 50000
#define N_EDGES 800000
#define N_GRAPHS 256
#define NCB 196        // coarse buckets = ceil(50000/256), dst>>8
#define CHUNK 3125     // edges per block in coarse passes (256 blocks)
#define GH_LEN (NCB * 256)   // 50176

// ---------------------------------------------------------------------------
// Dense GEMM v3 (R9 structure): lane = row, wave owns 16 cols, B via scalar
// path (wave-uniform pointers). v4: epilogue can emit fp16 (gathered operands
// HW1_2/HW1_3 are fp16 to halve downstream gather traffic).
// ---------------------------------------------------------------------------
template<int K, int NW, bool RELU>
__device__ __forceinline__ void stage_A(const float* __restrict__ X, float* As,
                                        int m0)
{
    constexpr int KP = K + 4;
    constexpr int T = NW * 64;
    for (int i = threadIdx.x * 4; i < 64 * K; i += T * 4) {
        int row = i / K;
        int col = i % K;
        int gm = m0 + row;
        float4 v = make_float4(0.f, 0.f, 0.f, 0.f);
        if (gm < N_NODES) v = *(const float4*)(X + (size_t)gm * K + col);
        if (RELU) {
            v.x = fmaxf(v.x, 0.f); v.y = fmaxf(v.y, 0.f);
            v.z = fmaxf(v.z, 0.f); v.w = fmaxf(v.w, 0.f);
        }
        *(float4*)(As + row * KP + col) = v;
    }
    __syncthreads();
}

template<int K>
__device__ __forceinline__ void gemm16(const float* arow,
                                       const float* __restrict__ Wcol,
                                       int wstride, float acc[16])
{
    #pragma unroll
    for (int j = 0; j < 16; ++j) acc[j] = 0.f;
    for (int k = 0; k < K; k += 4) {
        float4 a = *(const float4*)(arow + k);
        float av[4] = {a.x, a.y, a.z, a.w};
        #pragma unroll
        for (int kk = 0; kk < 4; ++kk) {
            const float* wr = Wcol + (k + kk) * wstride;   // uniform address
            #pragma unroll
            for (int j = 0; j < 16; ++j)
                acc[j] = fmaf(av[kk], wr[j], acc[j]);
        }
    }
}

__device__ __forceinline__ void store16f(float* orow, const float acc[16],
                                         const float* __restrict__ Bcol)
{
    #pragma unroll
    for (int j4 = 0; j4 < 4; ++j4) {
        float4 v = make_float4(acc[j4*4+0], acc[j4*4+1], acc[j4*4+2], acc[j4*4+3]);
        if (Bcol) {
            float4 b = *(const float4*)(Bcol + j4 * 4);
            v.x += b.x; v.y += b.y; v.z += b.z; v.w += b.w;
        }
        *(float4*)(orow + j4 * 4) = v;
    }
}

__device__ __forceinline__ void store16h(__half* orow, const float acc[16])
{
    __half2 hb[8];
    #pragma unroll
    for (int j = 0; j < 8; ++j)
        hb[j] = __float22half2_rn(make_float2(acc[2*j], acc[2*j+1]));
    *(uint4*)(orow)     = *(uint4*)&hb[0];
    *(uint4*)(orow + 8) = *(uint4*)&hb[4];
}

// Layer 1: CI (N x 64) @ WP (64 x 128) + b -> H1 fp32 (N x 128). 8 waves.
__global__ __launch_bounds__(512)
void dense1_kernel(const float* __restrict__ CI, const float* __restrict__ WP,
                   const float* __restrict__ Bias, float* __restrict__ H1)
{
    __shared__ float As[64 * 68];
    const int m0 = blockIdx.x * 64;
    stage_A<64, 8, false>(CI, As, m0);
    int wid = __builtin_amdgcn_readfirstlane(threadIdx.x >> 6);
    int lane = threadIdx.x & 63;
    float acc[16];
    gemm16<64>(As + lane * 68, WP + wid * 16, 128, acc);
    int gm = m0 + lane;
    if (gm < N_NODES)
        store16f(H1 + (size_t)gm * 128 + wid * 16, acc, Bias + wid * 16);
}

// Layer 2: relu(h1) (N x 128); waves 0-3 -> W1 -> HW1 fp16, 4-7 -> W2 -> AGG fp32+b.
__global__ __launch_bounds__(512)
void dense2_kernel(const float* __restrict__ X, const float* __restrict__ W1,
                   const float* __restrict__ W2, const float* __restrict__ Bias,
                   __half* __restrict__ HW1h, float* __restrict__ AGG)
{
    __shared__ float As[64 * 132];
    const int m0 = blockIdx.x * 64;
    stage_A<128, 8, true>(X, As, m0);
    int wid = __builtin_amdgcn_readfirstlane(threadIdx.x >> 6);
    int lane = threadIdx.x & 63;
    const float* Wc = (wid < 4) ? (W1 + wid * 16) : (W2 + (wid - 4) * 16);
    float acc[16];
    gemm16<128>(As + lane * 132, Wc, 64, acc);
    int gm = m0 + lane;
    if (gm < N_NODES) {
        if (wid < 4)
            store16h(HW1h + (size_t)gm * 64 + wid * 16, acc);
        else
            store16f(AGG + (size_t)gm * 64 + (wid - 4) * 16, acc,
                     Bias + (wid - 4) * 16);
    }
}

// Layer 3: relu(h2) (N x 64); waves 0-1 -> W1 -> HW1 fp16, 2-3 -> W2 -> AGG fp32+b.
__global__ __launch_bounds__(256)
void dense3_kernel(const float* __restrict__ X, const float* __restrict__ W1,
                   const float* __restrict__ W2, const float* __restrict__ Bias,
                   __half* __restrict__ HW1h, float* __restrict__ AGG)
{
    __shared__ float As[64 * 68];
    const int m0 = blockIdx.x * 64;
    stage_A<64, 4, true>(X, As, m0);
    int wid = __builtin_amdgcn_readfirstlane(threadIdx.x >> 6);
    int lane = threadIdx.x & 63;
    const float* Wc = (wid < 2) ? (W1 + wid * 16) : (W2 + (wid - 2) * 16);
    float acc[16];
    gemm16<64>(As + lane * 68, Wc, 32, acc);
    int gm = m0 + lane;
    if (gm < N_NODES) {
        if (wid < 2)
            store16h(HW1h + (size_t)gm * 32 + wid * 16, acc);
        else
            store16f(AGG + (size_t)gm * 32 + (wid - 2) * 16, acc,
                     Bias + (wid - 2) * 16);
    }
}

// ---------------------------------------------------------------------------
// CSR build (unchanged from R7/R9): two-pass counting sort, locality-local.
// ---------------------------------------------------------------------------
__global__ __launch_bounds__(256)
void c_hist(const int* __restrict__ ER, int* __restrict__ ghist)
{
    __shared__ int h[NCB];
    int t = threadIdx.x, blk = blockIdx.x;
    for (int i = t; i < NCB; i += 256) h[i] = 0;
    __syncthreads();
    int lo = blk * CHUNK, hi = lo + CHUNK;
    for (int e = lo + t; e < hi; e += 256) atomicAdd(&h[ER[e] >> 8], 1);
    __syncthreads();
    for (int i = t; i < NCB; i += 256) ghist[i * 256 + blk] = h[i];
}

__global__ __launch_bounds__(256)
void g_blocksum(const int* __restrict__ gh, int* __restrict__ bsum)
{
    __shared__ int red[4];
    int i = blockIdx.x * 256 + threadIdx.x;   // GH_LEN % 256 == 0
    int v = gh[i];
    #pragma unroll
    for (int off = 32; off; off >>= 1) v += __shfl_down(v, off, 64);
    if ((threadIdx.x & 63) == 0) red[threadIdx.x >> 6] = v;
    __syncthreads();
    if (threadIdx.x == 0) bsum[blockIdx.x] = red[0] + red[1] + red[2] + red[3];
}

__global__ __launch_bounds__(256)
void g_bscan(int* __restrict__ bsum)          // exclusive scan of NCB entries
{
    __shared__ int s[256];
    int t = threadIdx.x;
    int v = (t < NCB) ? bsum[t] : 0;
    s[t] = v;
    __syncthreads();
    for (int off = 1; off < 256; off <<= 1) {
        int u = (t >= off) ? s[t - off] : 0;
        __syncthreads();
        s[t] += u;
        __syncthreads();
    }
    if (t < NCB) bsum[t] = s[t] - v;
}

__global__ __launch_bounds__(256)
void g_apply(int* __restrict__ gh, const int* __restrict__ bsum)
{
    __shared__ int s[256];
    int t = threadIdx.x;
    int i = blockIdx.x * 256 + t;
    int v = gh[i];
    s[t] = v;
    __syncthreads();
    for (int off = 1; off < 256; off <<= 1) {
        int u = (t >= off) ? s[t - off] : 0;
        __syncthreads();
        s[t] += u;
        __syncthreads();
    }
    gh[i] = s[t] - v + bsum[blockIdx.x];      // exclusive, in place
}

__global__ __launch_bounds__(256)
void c_scatter(const int* __restrict__ ER, const int* __restrict__ EC,
               const float* __restrict__ EW, const int* __restrict__ gofs,
               int2* __restrict__ tmp)
{
    __shared__ int cur[NCB];
    int t = threadIdx.x, blk = blockIdx.x;
    for (int i = t; i < NCB; i += 256) cur[i] = gofs[i * 256 + blk];
    __syncthreads();
    int lo = blk * CHUNK, hi = lo + CHUNK;
    for (int e = lo + t; e < hi; e += 256) {
        int d = ER[e];
        int pos = atomicAdd(&cur[d >> 8], 1);
        tmp[pos] = make_int2(EC[e] | ((d & 255) << 16), __float_as_int(EW[e]));
    }
}

__global__ __launch_bounds__(256)
void bsort(const int2* __restrict__ tmp, const int* __restrict__ gofs,
           int2* __restrict__ packed, int* __restrict__ rowptr)
{
    __shared__ int hist[256];
    __shared__ int s[256];
    __shared__ int cur[256];
    int g = blockIdx.x, t = threadIdx.x;
    int base = gofs[g * 256];
    int end  = (g == NCB - 1) ? N_EDGES : gofs[(g + 1) * 256];
    hist[t] = 0;
    __syncthreads();
    for (int j = base + t; j < end; j += 256)
        atomicAdd(&hist[(tmp[j].x >> 16) & 255], 1);
    __syncthreads();
    int v = hist[t];
    s[t] = v;
    __syncthreads();
    for (int off = 1; off < 256; off <<= 1) {
        int u = (t >= off) ? s[t - off] : 0;
        __syncthreads();
        s[t] += u;
        __syncthreads();
    }
    int excl = s[t] - v;
    int n = g * 256 + t;
    if (n < N_NODES) rowptr[n] = base + excl;
    if (g == NCB - 1 && t == 0) rowptr[N_NODES] = N_EDGES;
    cur[t] = base + excl;
    __syncthreads();
    for (int j = base + t; j < end; j += 256) {
        int2 r = tmp[j];
        int pos = atomicAdd(&cur[(r.x >> 16) & 255], 1);
        packed[pos] = make_int2(r.x & 0xFFFF, r.y);
    }
}

// ---------------------------------------------------------------------------
// prep_kernel: fused pad (6250 blocks) + bounds (196) + wpack (32).
// pad: XPh[n][c] = fp16((c<30)?x[n][c]:0) ; CI[n][32+c] = fp32 same.
// ---------------------------------------------------------------------------
__global__ __launch_bounds__(256)
void prep_kernel(const float* __restrict__ X, const int* __restrict__ SEG,
                 const float* __restrict__ W1, const float* __restrict__ W2,
                 __half* __restrict__ XPh, float* __restrict__ CI,
                 int* __restrict__ start, float* __restrict__ WP)
{
    int bid = blockIdx.x;
    if (bid < 6250) {                       // pad: N*32 threads exactly
        int idx = bid * 256 + threadIdx.x;
        int n = idx >> 5;
        int c = idx & 31;
        float v = (c < 30) ? X[n * 30 + c] : 0.f;
        XPh[(size_t)n * 32 + c] = __float2half(v);
        CI[(size_t)n * 64 + 32 + c] = v;
    } else if (bid < 6250 + 196) {          // bounds
        int n = (bid - 6250) * 256 + threadIdx.x;
        if (n >= N_NODES) return;
        int g = SEG[n];
        int gprev = (n == 0) ? -1 : SEG[n - 1];
        for (int gg = gprev + 1; gg <= g; ++gg) start[gg] = n;
        if (n == N_NODES - 1)
            for (int gg = g + 1; gg <= N_GRAPHS; ++gg) start[gg] = N_NODES;
    } else {                                // wpack: 64 x 128
        int idx = (bid - 6446) * 256 + threadIdx.x;
        if (idx >= 64 * 128) return;
        int k = idx >> 7, c = idx & 127;
        float w = 0.f;
        if (k < 30) w = W1[k * 128 + c];
        else if (k >= 32 && k < 62) w = W2[(k - 32) * 128 + c];
        WP[idx] = w;
    }
}

// ---------------------------------------------------------------------------
// aggx_h: CI[n][0..31] = sum_j w_j * fp16 XPh[src_j][0..31]  (A @ X)
// 4 lanes/node x 8 features; 16B fp16 gather rows.
// ---------------------------------------------------------------------------
__global__ __launch_bounds__(256)
void aggx_h(const __half* __restrict__ XPh, const int* __restrict__ rowptr,
            const int2* __restrict__ packed, float* __restrict__ CI)
{
    int tid = threadIdx.x;
    int local = tid >> 2;
    int q = tid & 3;
    int n = blockIdx.x * 64 + local;
    if (n >= N_NODES) return;
    int r0 = rowptr[n], r1 = rowptr[n + 1];
    float4 acc0 = make_float4(0.f, 0.f, 0.f, 0.f);
    float4 acc1 = make_float4(0.f, 0.f, 0.f, 0.f);
    for (int j = r0; j < r1; ++j) {
        int2 r = packed[j];
        float w = __int_as_float(r.y);
        uint4 raw = *(const uint4*)(XPh + (size_t)r.x * 32 + q * 8);
        const __half2* hp = (const __half2*)&raw;
        float2 f0 = __half22float2(hp[0]);
        float2 f1 = __half22float2(hp[1]);
        float2 f2 = __half22float2(hp[2]);
        float2 f3 = __half22float2(hp[3]);
        acc0.x = fmaf(w, f0.x, acc0.x); acc0.y = fmaf(w, f0.y, acc0.y);
        acc0.z = fmaf(w, f1.x, acc0.z); acc0.w = fmaf(w, f1.y, acc0.w);
        acc1.x = fmaf(w, f2.x, acc1.x); acc1.y = fmaf(w, f2.y, acc1.y);
        acc1.z = fmaf(w, f3.x, acc1.z); acc1.w = fmaf(w, f3.y, acc1.w);
    }
    float* op = CI + (size_t)n * 64 + q * 8;
    *(float4*)op = acc0;
    *(float4*)(op + 4) = acc1;
}

// ---------------------------------------------------------------------------
// spmm_h (layers 2,3): fp16 gather rows, fp32 accumulate on top of AGG.
// FOUT/8 lanes per node (16B per lane per edge).
// ---------------------------------------------------------------------------
template<int FOUT>
__global__ __launch_bounds__(256)
void spmm_h(const __half* __restrict__ H, const int* __restrict__ rowptr,
            const int2* __restrict__ packed, float* __restrict__ AGG)
{
    constexpr int T = FOUT / 8;
    int tid = threadIdx.x;
    int local = tid / T;
    int q = tid % T;
    int n = blockIdx.x * (256 / T) + local;
    if (n >= N_NODES) return;
    int r0 = rowptr[n], r1 = rowptr[n + 1];
    float* ap = AGG + (size_t)n * FOUT + q * 8;
    float4 acc0 = *(const float4*)ap;
    float4 acc1 = *(const float4*)(ap + 4);
    for (int j = r0; j < r1; ++j) {
        int2 r = packed[j];
        float w = __int_as_float(r.y);
        uint4 raw = *(const uint4*)(H + (size_t)r.x * FOUT + q * 8);
        const __half2* hp = (const __half2*)&raw;
        float2 f0 = __half22float2(hp[0]);
        float2 f1 = __half22float2(hp[1]);
        float2 f2 = __half22float2(hp[2]);
        float2 f3 = __half22float2(hp[3]);
        acc0.x = fmaf(w, f0.x, acc0.x); acc0.y = fmaf(w, f0.y, acc0.y);
        acc0.z = fmaf(w, f1.x, acc0.z); acc0.w = fmaf(w, f1.y, acc0.w);
        acc1.x = fmaf(w, f2.x, acc1.x); acc1.y = fmaf(w, f2.y, acc1.y);
        acc1.z = fmaf(w, f3.x, acc1.z); acc1.w = fmaf(w, f3.y, acc1.w);
    }
    *(float4*)ap = acc0;
    *(float4*)(ap + 4) = acc1;
}

// ---------------------------------------------------------------------------
// pool + head fused: one block/graph; mean of relu(H) then softmax(p@wd+bd).
// ---------------------------------------------------------------------------
__global__ __launch_bounds__(256)
void pool_kernel(const float* __restrict__ H, const int* __restrict__ start,
                 const float* __restrict__ WD, const float* __restrict__ BD,
                 float* __restrict__ OUT)
{
    __shared__ float red[8][33];
    int g = blockIdx.x;
    int s = start[g], e = start[g + 1];
    int q = threadIdx.x & 31;
    int lane = threadIdx.x >> 5;
    float acc = 0.f;
    for (int n = s + lane; n < e; n += 8)
        acc += fmaxf(H[(size_t)n * 32 + q], 0.f);
    red[lane][q] = acc;
    __syncthreads();
    if (threadIdx.x < 32) {
        float v = 0.f;
        #pragma unroll
        for (int i = 0; i < 8; ++i) v += red[i][q];
        float inv = (e > s) ? 1.0f / (float)(e - s) : 1.0f;
        float p = v * inv;
        float p0 = p * WD[q * 2 + 0];
        float p1 = p * WD[q * 2 + 1];
        #pragma unroll
        for (int off = 16; off; off >>= 1) {
            p0 += __shfl_down(p0, off, 32);
            p1 += __shfl_down(p1, off, 32);
        }
        if (q == 0) {
            float l0 = p0 + BD[0], l1 = p1 + BD[1];
            float m = fmaxf(l0, l1);
            float e0 = expf(l0 - m), e1 = expf(l1 - m);
            float si = 1.0f / (e0 + e1);
            OUT[g * 2 + 0] = e0 * si;
            OUT[g * 2 + 1] = e1 * si;
        }
    }
}

extern "C" void kernel_launch(void* const* d_in, const int* in_sizes, int n_in,
                              void* d_out, int out_size, void* d_ws, size_t ws_size,
                              hipStream_t stream)
{
    const float* x    = (const float*)d_in[0];
    const float* ew   = (const float*)d_in[1];
    const int*   er   = (const int*)d_in[2];
    const int*   ec   = (const int*)d_in[3];
    const int*   seg  = (const int*)d_in[4];
    const float* w1_1 = (const float*)d_in[5];
    const float* w2_1 = (const float*)d_in[6];
    const float* b_1  = (const float*)d_in[7];
    const float* w1_2 = (const float*)d_in[8];
    const float* w2_2 = (const float*)d_in[9];
    const float* b_2  = (const float*)d_in[10];
    const float* w1_3 = (const float*)d_in[11];
    const float* w2_3 = (const float*)d_in[12];
    const float* b_3  = (const float*)d_in[13];
    const float* wd   = (const float*)d_in[14];
    const float* bd   = (const float*)d_in[15];

    float* ws = (float*)d_ws;
    // Phase 1: CI fp32 (0..3.2M), XPh fp16 (3.2M..4.0M), B=h1 fp32 (6.4..12.8M)
    float*  CI   = ws;                         // N x 64 fp32
    __half* XPh  = (__half*)(ws + 3200000);    // N x 32 fp16
    float*  B    = ws + 6400000;               // N x 128 fp32 (h1)
    int2*   tmp  = (int2*)(ws + 6400000);      // E x int2 (CSR build; dead before h1)
    // Phase 2: H2h fp16 at 0 (CI dead), A2=h2 fp32 at 3.2M (XPh dead)
    __half* H2h  = (__half*)ws;                // N x 64 fp16
    float*  A2   = ws + 3200000;               // N x 64 fp32 (h2)
    // Phase 3: H3h fp16 at 6.4M (B dead), B2=h3 fp32 at 8.0M
    __half* H3h  = (__half*)(ws + 6400000);    // N x 32 fp16
    float*  B2   = ws + 8000000;               // N x 32 fp32 (h3)
    int*    IW   = (int*)d_ws;
    int2*   packed = (int2*)(IW + 12800000);   // E x {src, w}
    int*    rowptr = IW + 14400000;            // N+1
    int*    gofs   = IW + 14460000;            // GH_LEN
    int*    bsum   = IW + 14515000;            // NCB
    int*    start  = IW + 14520000;            // G+1
    float*  WP     = ws + 14540000;            // 64 x 128 packed layer-1 weights

    dim3 blk(256);
    const int MB = (N_NODES + 63) / 64;        // 782

    // ---- CSR build: locality-preserving two-pass counting sort ----
    c_hist<<<dim3(256), blk, 0, stream>>>(er, gofs);
    g_blocksum<<<dim3(GH_LEN / 256), blk, 0, stream>>>(gofs, bsum);
    g_bscan<<<dim3(1), blk, 0, stream>>>(bsum);
    g_apply<<<dim3(GH_LEN / 256), blk, 0, stream>>>(gofs, bsum);
    c_scatter<<<dim3(256), blk, 0, stream>>>(er, ec, ew, gofs, tmp);
    bsort<<<dim3(NCB), blk, 0, stream>>>(tmp, gofs, packed, rowptr);

    // ---- prep: pad (XPh, CI) + bounds + wpack, fused ----
    prep_kernel<<<dim3(6478), blk, 0, stream>>>(x, seg, w1_1, w2_1, XPh, CI, start, WP);

    // Layer 1: CI = [A@X | X], h1 = CI @ wpack + b
    aggx_h<<<dim3(MB), blk, 0, stream>>>(XPh, rowptr, packed, CI);
    dense1_kernel<<<dim3(MB), dim3(512), 0, stream>>>(CI, WP, b_1, B);
    // Layer 2: relu(h1)(128) -> 64; HW1 fp16
    dense2_kernel<<<dim3(MB), dim3(512), 0, stream>>>(B, w1_2, w2_2, b_2, H2h, A2);
    spmm_h<64><<<dim3((N_NODES + 31) / 32), blk, 0, stream>>>(H2h, rowptr, packed, A2);
    // Layer 3: relu(h2)(64) -> 32; HW1 fp16
    dense3_kernel<<<dim3(MB), blk, 0, stream>>>(A2, w1_3, w2_3, b_3, H3h, B2);
    spmm_h<32><<<dim3(MB), blk, 0, stream>>>(H3h, rowptr, packed, B2);

    // Pool + head (fused, atomic-free)
    pool_kernel<<<dim3(N_GRAPHS), blk, 0, stream>>>(B2, start, wd, bd, (float*)d_out);
}